// Round 3
// baseline (365.979 us; speedup 1.0000x reference)
//
#include <hip/hip_runtime.h>

// ZBL pair potential + segment-sum into per-atom energies.
// Inputs (setup_inputs order):
//   d_in[0] Z            (4,)     float32
//   d_in[1] r            (E,)     float32   E = 6,400,000
//   d_in[2] per_atom_energy (N,1) float32   N = 100,000
//   d_in[3] atom_types   (N,)     int32
//   d_in[4] edge_index   (2,E)    int32
// Output: (N,1) float32 = segment_sum(edge_eng, edge_index[0]) + per_atom_energy
//
// R2 post-mortem: WRITE_SIZE identical with unsafe atomics + 16 replicas =>
// bound by device-scope atomic fabric op rate (~24.5 Gops/s), not CAS loops
// or line contention. R3: perform atomics IN the local XCD L2 (no sc bits,
// plain global_atomic_add_f32 via inline asm) into per-XCD replicas indexed
// by the physical XCC_ID (s_getreg, HW-verified 0-7 on MI355X). Kernel-end
// release writes dirty L2 lines back; reduce kernel sums the replicas.

namespace {
constexpr float PZBL     = 0.23f;
constexpr float A0_INV   = 1.0f / 0.4685f;
constexpr float C1 = 0.02817f, C2 = 0.28022f, C3 = 0.50986f, C4 = 0.18175f;
constexpr float D1 = -0.20162f, D2 = -0.4029f, D3 = -0.94229f, D4 = -3.1998f;
constexpr float QQ       = 14.399645f * 0.5f;
constexpr float RMAX_INV = 1.0f / 6.0f;
constexpr int   N_REP    = 16;   // 8 XCDs x 2 sub-replicas
}

// Physical XCD id of this wave's CU (wave-uniform). Measured reliable on
// MI355X (learn_hip m09). Masked to 8 XCDs.
__device__ __forceinline__ int xcc_id() {
    int x;
    asm("s_getreg_b32 %0, hwreg(HW_REG_XCC_ID)" : "=s"(x));
    return x & 7;
}

// Native f32 atomic add with NO scope/cache bits: performed in the local
// XCD's L2 (TCC), stays dirty there, written back at kernel-end release.
// Safe only because replica index == physical XCD id (no cross-XCD RMW on
// the same line). Fire-and-forget: no return, no waitcnt needed.
__device__ __forceinline__ void l2_atomic_add(float* p, float v) {
    asm volatile("global_atomic_add_f32 %0, %1, off" :: "v"(p), "v"(v) : "memory");
}

// {Z, Z^0.23} table into workspace (ws re-poisoned every call -> recompute).
__global__ void zbl_table_kernel(const float* __restrict__ Z,
                                 float* __restrict__ tbl) {
    int t = threadIdx.x;
    if (t < 4) {
        float z = Z[t];
        tbl[t]     = z;
        tbl[4 + t] = powf(z, PZBL);
    }
}

// Fallback-path init: out = per_atom_energy.
__global__ void zbl_init_out(const float* __restrict__ pae,
                             float* __restrict__ out, int n) {
    int i = blockIdx.x * blockDim.x + threadIdx.x;
    if (i < n) out[i] = pae[i];
}

__device__ __forceinline__ void zbl_one_edge(float rk, int ia, int ib,
                                             const int* __restrict__ types,
                                             const float* s_z, const float* s_zp,
                                             float* __restrict__ dst,
                                             bool l2_scope) {
    float rr = rk * RMAX_INV;
    int ti = types[ia];
    int tj = types[ib];
    float zi = s_z[ti], zj = s_z[tj];
    float x = (s_zp[ti] + s_zp[tj]) * rk * A0_INV;
    float psi = C1 * __expf(D1 * x) + C2 * __expf(D2 * x)
              + C3 * __expf(D3 * x) + C4 * __expf(D4 * x);
    float eng = QQ * zi * zj * psi / rk;
    // p=6 polynomial cutoff: 1 - 28 rr^6 + 48 rr^7 - 21 rr^8
    float rr2 = rr * rr;
    float rr3 = rr2 * rr;
    float rr6 = rr3 * rr3;
    float cutoff = 1.0f + rr6 * (-28.0f + rr * (48.0f - 21.0f * rr));
    if (rr < 1.0f) {
        float e = cutoff * eng;
        if (l2_scope) l2_atomic_add(&dst[ia], e);
        else          unsafeAtomicAdd(&dst[ia], e);   // fallback: device scope
    }
}

__global__ __launch_bounds__(256) void zbl_edge_kernel(
    const float* __restrict__ r,
    const int*   __restrict__ ei0,   // edge_index row 0 (dest atoms)
    const int*   __restrict__ ei1,   // edge_index row 1
    const int*   __restrict__ types,
    const float* __restrict__ tbl,
    float*       __restrict__ copies,  // N_REP replicas, each n_atoms floats
    int n_atoms,
    int n_quads) {
    __shared__ float s_z[4];
    __shared__ float s_zp[4];
    if (threadIdx.x < 8) {
        if (threadIdx.x < 4) s_z[threadIdx.x] = tbl[threadIdx.x];
        else                 s_zp[threadIdx.x - 4] = tbl[threadIdx.x];
    }
    __syncthreads();

    // Replica = physical XCD * 2 + block parity. All RMWs to a given replica
    // come from one XCD => safe to perform them in that XCD's L2.
    int rep = (xcc_id() << 1) | (int)(blockIdx.x & 1);
    float* dst = copies + (size_t)rep * n_atoms;

    int q = blockIdx.x * blockDim.x + threadIdx.x;
    if (q >= n_quads) return;

    float4 rv = ((const float4*)r)[q];
    int4   av = ((const int4*)ei0)[q];
    int4   bv = ((const int4*)ei1)[q];

    zbl_one_edge(rv.x, av.x, bv.x, types, s_z, s_zp, dst, true);
    zbl_one_edge(rv.y, av.y, bv.y, types, s_z, s_zp, dst, true);
    zbl_one_edge(rv.z, av.z, bv.z, types, s_z, s_zp, dst, true);
    zbl_one_edge(rv.w, av.w, bv.w, types, s_z, s_zp, dst, true);
}

// Scalar tail for n_edges % 4 != 0 (not hit for E = 6.4M).
__global__ void zbl_edge_tail(const float* __restrict__ r,
                              const int* __restrict__ ei0,
                              const int* __restrict__ ei1,
                              const int* __restrict__ types,
                              const float* __restrict__ tbl,
                              float* __restrict__ copies,
                              int n_atoms,
                              int start, int n_edges) {
    __shared__ float s_z[4];
    __shared__ float s_zp[4];
    if (threadIdx.x < 8) {
        if (threadIdx.x < 4) s_z[threadIdx.x] = tbl[threadIdx.x];
        else                 s_zp[threadIdx.x - 4] = tbl[threadIdx.x];
    }
    __syncthreads();
    float* dst = copies + (size_t)(xcc_id() << 1) * n_atoms;
    int e = start + threadIdx.x;
    if (e < n_edges) {
        zbl_one_edge(r[e], ei0[e], ei1[e], types, s_z, s_zp, dst, true);
    }
}

// out = pae + sum over N_REP replicas (reads ~6.8 MB, writes 0.4 MB).
__global__ void zbl_reduce_out(const float* __restrict__ pae,
                               const float* __restrict__ copies,
                               float* __restrict__ out,
                               int n, int k) {
    int i = blockIdx.x * blockDim.x + threadIdx.x;
    if (i >= n) return;
    float s = pae[i];
    for (int c = 0; c < k; ++c) s += copies[(size_t)c * n + i];
    out[i] = s;
}

// Fallback edge kernel: device-scope atomics straight into out.
__global__ __launch_bounds__(256) void zbl_edge_fallback(
    const float* __restrict__ r,
    const int*   __restrict__ ei0,
    const int*   __restrict__ ei1,
    const int*   __restrict__ types,
    const float* __restrict__ tbl,
    float*       __restrict__ out,
    int n_quads) {
    __shared__ float s_z[4];
    __shared__ float s_zp[4];
    if (threadIdx.x < 8) {
        if (threadIdx.x < 4) s_z[threadIdx.x] = tbl[threadIdx.x];
        else                 s_zp[threadIdx.x - 4] = tbl[threadIdx.x];
    }
    __syncthreads();
    int q = blockIdx.x * blockDim.x + threadIdx.x;
    if (q >= n_quads) return;
    float4 rv = ((const float4*)r)[q];
    int4   av = ((const int4*)ei0)[q];
    int4   bv = ((const int4*)ei1)[q];
    zbl_one_edge(rv.x, av.x, bv.x, types, s_z, s_zp, out, false);
    zbl_one_edge(rv.y, av.y, bv.y, types, s_z, s_zp, out, false);
    zbl_one_edge(rv.z, av.z, bv.z, types, s_z, s_zp, out, false);
    zbl_one_edge(rv.w, av.w, bv.w, types, s_z, s_zp, out, false);
}

extern "C" void kernel_launch(void* const* d_in, const int* in_sizes, int n_in,
                              void* d_out, int out_size, void* d_ws, size_t ws_size,
                              hipStream_t stream) {
    const float* Z     = (const float*)d_in[0];
    const float* r     = (const float*)d_in[1];
    const float* pae   = (const float*)d_in[2];
    const int*   types = (const int*)d_in[3];
    const int*   ei    = (const int*)d_in[4];

    const int n_edges = in_sizes[1];
    const int n_atoms = in_sizes[2];

    float* out = (float*)d_out;
    float* tbl = (float*)d_ws;
    float* copies = tbl + 8;

    const bool use_copies =
        (8 + (size_t)N_REP * n_atoms) * sizeof(float) <= ws_size;

    zbl_table_kernel<<<1, 64, 0, stream>>>(Z, tbl);

    const int n_quads = n_edges >> 2;
    const int rem     = n_edges & 3;

    if (use_copies) {
        hipMemsetAsync(copies, 0, (size_t)N_REP * n_atoms * sizeof(float), stream);
        if (n_quads > 0) {
            zbl_edge_kernel<<<(n_quads + 255) / 256, 256, 0, stream>>>(
                r, ei, ei + n_edges, types, tbl, copies, n_atoms, n_quads);
        }
        if (rem) {
            zbl_edge_tail<<<1, 64, 0, stream>>>(r, ei, ei + n_edges, types, tbl,
                                                copies, n_atoms,
                                                n_edges - rem, n_edges);
        }
        zbl_reduce_out<<<(n_atoms + 255) / 256, 256, 0, stream>>>(
            pae, copies, out, n_atoms, N_REP);
    } else {
        zbl_init_out<<<(n_atoms + 255) / 256, 256, 0, stream>>>(pae, out, n_atoms);
        if (n_quads > 0) {
            zbl_edge_fallback<<<(n_quads + 255) / 256, 256, 0, stream>>>(
                r, ei, ei + n_edges, types, tbl, out, n_quads);
        }
    }
}

// Round 4
// 191.536 us; speedup vs baseline: 1.9108x; 1.9108x over previous
//
#include <hip/hip_runtime.h>

// ZBL pair potential + segment-sum into per-atom energies.
// Inputs (setup_inputs order):
//   d_in[0] Z            (4,)     float32
//   d_in[1] r            (E,)     float32   E = 6,400,000
//   d_in[2] per_atom_energy (N,1) float32   N = 100,000
//   d_in[3] atom_types   (N,)     int32
//   d_in[4] edge_index   (2,E)    int32
// Output: (N,1) float32 = segment_sum(edge_eng, edge_index[0]) + per_atom_energy
//
// R2/R3 post-mortem: WRITE_SIZE byte-identical (163 MB = 6.4M x ~26B) across
// device-scope atomics, unsafe atomics, 16 replicas, and XCD-local no-sc-bit
// atomics => global f32 atomics execute at a memory-side coherence point at
// ~25 Gops/s no matter what. The op COUNT must go to zero.
// R4: chunked LDS histogram. C=4 chunks x 25600 atoms (100 KB LDS bins),
// S=64 edge slices; block (c,s) scans slice s, ds_add_f32 for dests in chunk
// c, then flushes bins to a private d_ws region with plain stores (no
// atomics). A reduce kernel sums the S partials per chunk + per_atom_energy.

namespace {
constexpr float PZBL     = 0.23f;
constexpr float A0_INV   = 1.0f / 0.4685f;
constexpr float C1 = 0.02817f, C2 = 0.28022f, C3 = 0.50986f, C4 = 0.18175f;
constexpr float D1 = -0.20162f, D2 = -0.4029f, D3 = -0.94229f, D4 = -3.1998f;
constexpr float QQ       = 14.399645f * 0.5f;
constexpr float RMAX_INV = 1.0f / 6.0f;
constexpr int   CHUNK    = 25600;   // atoms per LDS chunk -> 100 KB fp32 bins
constexpr int   BLOCK    = 1024;    // 16 waves/CU at 1 block/CU
constexpr int   S_MAX    = 64;      // edge slices (partials = C*S*CHUNK floats)
}

// {Z, Z^0.23} table into workspace (ws re-poisoned every call -> recompute).
__global__ void zbl_table_kernel(const float* __restrict__ Z,
                                 float* __restrict__ tbl) {
    int t = threadIdx.x;
    if (t < 4) {
        float z = Z[t];
        tbl[t]     = z;
        tbl[4 + t] = powf(z, PZBL);
    }
}

__device__ __forceinline__ float zbl_energy(float rk, int ia, int ib,
                                            const int* __restrict__ types,
                                            const float* s_z, const float* s_zp) {
    float rr = rk * RMAX_INV;
    int ti = types[ia];
    int tj = types[ib];
    float zi = s_z[ti], zj = s_z[tj];
    float x = (s_zp[ti] + s_zp[tj]) * rk * A0_INV;
    float psi = C1 * __expf(D1 * x) + C2 * __expf(D2 * x)
              + C3 * __expf(D3 * x) + C4 * __expf(D4 * x);
    float eng = QQ * zi * zj * psi / rk;
    // p=6 polynomial cutoff: 1 - 28 rr^6 + 48 rr^7 - 21 rr^8
    float rr2 = rr * rr;
    float rr3 = rr2 * rr;
    float rr6 = rr3 * rr3;
    float cutoff = 1.0f + rr6 * (-28.0f + rr * (48.0f - 21.0f * rr));
    return cutoff * eng;
}

// Per-edge: membership + cutoff early-outs (skips types gathers + exp for
// ~75% + 18% of edges), then LDS atomic (ds_add_f32 — CU-local, cheap).
__device__ __forceinline__ void zbl_edge_lds(float rk, int ia, int ib, int base,
                                             const int* __restrict__ types,
                                             const float* s_z, const float* s_zp,
                                             float* bins) {
    unsigned d = (unsigned)(ia - base);
    if (d >= (unsigned)CHUNK) return;
    if (rk * RMAX_INV >= 1.0f) return;
    atomicAdd(&bins[d], zbl_energy(rk, ia, ib, types, s_z, s_zp));
}

__global__ __launch_bounds__(BLOCK) void zbl_chunk_kernel(
    const float* __restrict__ r,
    const int*   __restrict__ ei0,
    const int*   __restrict__ ei1,
    const int*   __restrict__ types,
    const float* __restrict__ tbl,
    float*       __restrict__ partials,   // [C*S][CHUNK]
    int n_chunks, int n_slices, int quads_per_slice,
    int n_quads, int n_edges) {
    __shared__ float s_z[4];
    __shared__ float s_zp[4];
    __shared__ float bins[CHUNK];         // 100 KB

    int tid = threadIdx.x;
    if (tid < 8) {
        if (tid < 4) s_z[tid] = tbl[tid];
        else         s_zp[tid - 4] = tbl[tid];
    }
    for (int i = tid; i < CHUNK; i += BLOCK) bins[i] = 0.0f;
    __syncthreads();

    const int c = blockIdx.x % n_chunks;
    const int s = blockIdx.x / n_chunks;
    const int base = c * CHUNK;

    const int q0 = s * quads_per_slice;
    const int q1 = min(n_quads, q0 + quads_per_slice);
    const float4* r4 = (const float4*)r;
    const int4*   a4 = (const int4*)ei0;
    const int4*   b4 = (const int4*)ei1;

    for (int q = q0 + tid; q < q1; q += BLOCK) {
        float4 rv = r4[q];
        int4   av = a4[q];
        int4   bv = b4[q];
        zbl_edge_lds(rv.x, av.x, bv.x, base, types, s_z, s_zp, bins);
        zbl_edge_lds(rv.y, av.y, bv.y, base, types, s_z, s_zp, bins);
        zbl_edge_lds(rv.z, av.z, bv.z, base, types, s_z, s_zp, bins);
        zbl_edge_lds(rv.w, av.w, bv.w, base, types, s_z, s_zp, bins);
    }
    // Scalar tail (n_edges % 4) — handled once, by the s==0 slice blocks.
    if (s == 0) {
        for (int e = 4 * n_quads + tid; e < n_edges; e += BLOCK) {
            zbl_edge_lds(r[e], ei0[e], ei1[e], base, types, s_z, s_zp, bins);
        }
    }
    __syncthreads();

    // Non-atomic flush: every block owns a private CHUNK region.
    float* dst = partials + (size_t)blockIdx.x * CHUNK;
    for (int i = tid; i < CHUNK; i += BLOCK) dst[i] = bins[i];
}

// out[a] = pae[a] + sum over slices of partial[(s*C + c)][a - c*CHUNK].
__global__ void zbl_reduce_out(const float* __restrict__ pae,
                               const float* __restrict__ partials,
                               float* __restrict__ out,
                               int n_atoms, int n_chunks, int n_slices) {
    int a = blockIdx.x * blockDim.x + threadIdx.x;
    if (a >= n_atoms) return;
    int c = a / CHUNK;
    int i = a - c * CHUNK;
    const float* p = partials + (size_t)c * CHUNK + i;
    const size_t stride = (size_t)n_chunks * CHUNK;
    float sum = pae[a];
    for (int s = 0; s < n_slices; ++s) sum += p[(size_t)s * stride];
    out[a] = sum;
}

// ---------- fallback path (ws too small): device-scope atomics into out ----
__global__ void zbl_init_out(const float* __restrict__ pae,
                             float* __restrict__ out, int n) {
    int i = blockIdx.x * blockDim.x + threadIdx.x;
    if (i < n) out[i] = pae[i];
}

__global__ __launch_bounds__(256) void zbl_edge_fallback(
    const float* __restrict__ r,
    const int*   __restrict__ ei0,
    const int*   __restrict__ ei1,
    const int*   __restrict__ types,
    const float* __restrict__ tbl,
    float*       __restrict__ out,
    int n_edges) {
    __shared__ float s_z[4];
    __shared__ float s_zp[4];
    if (threadIdx.x < 8) {
        if (threadIdx.x < 4) s_z[threadIdx.x] = tbl[threadIdx.x];
        else                 s_zp[threadIdx.x - 4] = tbl[threadIdx.x];
    }
    __syncthreads();
    int e = blockIdx.x * blockDim.x + threadIdx.x;
    if (e >= n_edges) return;
    float rk = r[e];
    if (rk * RMAX_INV >= 1.0f) return;
    unsafeAtomicAdd(&out[ei0[e]],
                    zbl_energy(rk, ei0[e], ei1[e], types, s_z, s_zp));
}

extern "C" void kernel_launch(void* const* d_in, const int* in_sizes, int n_in,
                              void* d_out, int out_size, void* d_ws, size_t ws_size,
                              hipStream_t stream) {
    const float* Z     = (const float*)d_in[0];
    const float* r     = (const float*)d_in[1];
    const float* pae   = (const float*)d_in[2];
    const int*   types = (const int*)d_in[3];
    const int*   ei    = (const int*)d_in[4];

    const int n_edges = in_sizes[1];
    const int n_atoms = in_sizes[2];

    float* out = (float*)d_out;
    float* tbl = (float*)d_ws;
    float* partials = tbl + 8;

    zbl_table_kernel<<<1, 64, 0, stream>>>(Z, tbl);

    const int n_chunks = (n_atoms + CHUNK - 1) / CHUNK;   // 4 for N=100K

    // Pick slice count that fits the workspace.
    int S = S_MAX;
    while (S > 1 &&
           (8 + (size_t)n_chunks * S * CHUNK) * sizeof(float) > ws_size) {
        S >>= 1;
    }
    const bool use_lds_path =
        (8 + (size_t)n_chunks * S * CHUNK) * sizeof(float) <= ws_size;

    if (use_lds_path) {
        // int4 casts on ei1 = ei + n_edges need 16B alignment; if n_edges is
        // not a multiple of 4, process everything through the scalar tail.
        const int n_quads = (n_edges & 3) ? 0 : (n_edges >> 2);
        const int quads_per_slice = (n_quads + S - 1) / S;
        zbl_chunk_kernel<<<n_chunks * S, BLOCK, 0, stream>>>(
            r, ei, ei + n_edges, types, tbl, partials,
            n_chunks, S, quads_per_slice, n_quads, n_edges);
        zbl_reduce_out<<<(n_atoms + 255) / 256, 256, 0, stream>>>(
            pae, partials, out, n_atoms, n_chunks, S);
    } else {
        zbl_init_out<<<(n_atoms + 255) / 256, 256, 0, stream>>>(pae, out, n_atoms);
        zbl_edge_fallback<<<(n_edges + 255) / 256, 256, 0, stream>>>(
            r, ei, ei + n_edges, types, tbl, out, n_edges);
    }
}